// Round 9
// baseline (150.780 us; speedup 1.0000x reference)
//
#include <hip/hip_runtime.h>

// GAT layer fused, MI355X gfx950 — v9: 32-rows/wave flash (2x16 row-subtiles
// sharing every staged K/V fragment -> LDS bytes/row halved), 128-row tiles,
// ~520 working blocks = 1 capacity round. Pure-sum softmax, in-loop adj.
// Pipeline: memset -> prep_k (conv|count|packW fused) -> hnew_k -> attn_k -> comb_k.

typedef __attribute__((ext_vector_type(8))) short short8;   // 8 x bf16 (4 VGPR)
typedef __attribute__((ext_vector_type(4))) float f32x4;    // MFMA C/D frag

#define NN 8192
#define DD 256
#define NEGB -1.2983e16f  // -9e15 * log2(e): NEG_BIG in base-2 softmax domain

__device__ __forceinline__ unsigned short f2bf(float f) {
  unsigned u = __builtin_bit_cast(unsigned, f);
  u += 0x7FFFu + ((u >> 16) & 1u);  // RNE
  return (unsigned short)(u >> 16);
}
__device__ __forceinline__ float bf2f(unsigned short s) {
  unsigned u = ((unsigned)s) << 16;
  return __builtin_bit_cast(float, u);
}
__device__ __forceinline__ f32x4 mfma16(short8 a, short8 b, f32x4 c) {
  return __builtin_amdgcn_mfma_f32_16x16x32_bf16(a, b, c, 0, 0, 0);
}
// async global->LDS, 16B per lane; lds ptr wave-uniform base
__device__ __forceinline__ void gld16(const unsigned short* g, unsigned short* l) {
  __builtin_amdgcn_global_load_lds(
      (const __attribute__((address_space(1))) void*)g,
      (__attribute__((address_space(3))) void*)l, 16, 0, 0);
}

// ---- fused prep: conv_h (blocks 0..2047) | count_k (2048..2079) | pack_wf --
__global__ __launch_bounds__(256) void prep_k(const float* __restrict__ h,
                                              const float* __restrict__ W,
                                              const int* __restrict__ adj,
                                              unsigned short* __restrict__ hQf,
                                              unsigned short* __restrict__ Wf,
                                              int* __restrict__ kout) {
  const int bx = blockIdx.x, tid = threadIdx.x;
  if (bx < 2048) {  // h (f32) -> hQf bf16 MFMA frags
    int gid = bx * 256 + tid;
    int i = gid >> 6, k4 = (gid & 63) * 4;
    float4 v = *(const float4*)(h + (size_t)i * DD + k4);
    size_t off = ((size_t)((i >> 4) * 8 + (k4 >> 5)) * 64 +
                  (((k4 >> 3) & 3) * 16 + (i & 15))) * 8 + (k4 & 7);
    ushort4 o;
    o.x = f2bf(v.x); o.y = f2bf(v.y); o.z = f2bf(v.z); o.w = f2bf(v.w);
    *(ushort4*)(hQf + off) = o;
  } else if (bx < 2080) {  // k = sum(adj[:,0] != 0)
    __shared__ int red[256];
    int gid = (bx - 2048) * 256 + tid;
    red[tid] = (adj[(size_t)gid * NN] != 0);
    __syncthreads();
    for (int off = 128; off; off >>= 1) {
      if (tid < off) red[tid] += red[tid + off];
      __syncthreads();
    }
    if (tid == 0) atomicAdd(kout, red[0]);
  } else {  // W -> bf16 B-frags
    int gid = (bx - 2080) * 256 + tid;
    int l = gid & 63, f = gid >> 6, n16 = f >> 3, kk = f & 7;
    int lr = l & 15, lg = l >> 4;
    const float* src = W + (size_t)(n16 * 16 + lr) * DD + kk * 32 + lg * 8;
    float4 w0 = *(const float4*)src, w1 = *(const float4*)(src + 4);
    short8 o;
    o[0] = (short)f2bf(w0.x); o[1] = (short)f2bf(w0.y);
    o[2] = (short)f2bf(w0.z); o[3] = (short)f2bf(w0.w);
    o[4] = (short)f2bf(w1.x); o[5] = (short)f2bf(w1.y);
    o[6] = (short)f2bf(w1.z); o[7] = (short)f2bf(w1.w);
    *(short8*)(Wf + (size_t)gid * 8) = o;
  }
}

// ---- h_new = h @ W^T + b -> hnb (row-major) + hnV (PV B-frags, ushort4) ---
__global__ __launch_bounds__(256) void hnew_k(const unsigned short* __restrict__ hQf,
                                              const unsigned short* __restrict__ Wf,
                                              const float* __restrict__ bias,
                                              unsigned short* __restrict__ hnb,
                                              unsigned short* __restrict__ hnV) {
  const int tid = threadIdx.x, w = tid >> 6, l = tid & 63, lr = l & 15, lg = l >> 4;
  const int row0 = blockIdx.x * 64 + w * 16;

  short8 a[8];
#pragma unroll
  for (int kk = 0; kk < 8; ++kk)
    a[kk] = *(const short8*)(hQf + ((size_t)((row0 >> 4) * 8 + kk) * 64 + l) * 8);

  f32x4 acc[16];
#pragma unroll
  for (int nt = 0; nt < 16; ++nt) acc[nt] = (f32x4){0.f, 0.f, 0.f, 0.f};

#pragma unroll
  for (int kk = 0; kk < 8; ++kk)
#pragma unroll
    for (int nt = 0; nt < 16; ++nt) {
      short8 bf = *(const short8*)(Wf + ((size_t)(nt * 8 + kk) * 64 + l) * 8);
      acc[nt] = mfma16(a[kk], bf, acc[nt]);
    }
  const int rowbase = row0 + lg * 4;  // q = 0..3 contiguous, no 8-boundary cross
#pragma unroll
  for (int nt = 0; nt < 16; ++nt) {
    const int col = nt * 16 + lr;
    const float bv = bias[col];
    ushort4 o4;
    unsigned short r16[4];
#pragma unroll
    for (int q = 0; q < 4; ++q) r16[q] = f2bf(acc[nt][q] + bv);
    o4.x = r16[0]; o4.y = r16[1]; o4.z = r16[2]; o4.w = r16[3];
#pragma unroll
    for (int q = 0; q < 4; ++q) hnb[(size_t)(rowbase + q) * DD + col] = r16[q];
    *(ushort4*)(hnV + ((size_t)((rowbase >> 5) * 16 + nt) * 64 +
                       ((rowbase >> 3) & 3) * 16 + lr) * 8 + (rowbase & 7)) = o4;
  }
}

// ---- flash attention partials: 32 rows/wave (2 subtiles), 128-row tiles ---
// Grid (S=16 chunks, 64 tiles). Every staged K/V fragment is read from LDS
// once and used by BOTH row-subtiles -> LDS bytes per row halved vs v8.
__global__ __launch_bounds__(256, 2) void attn_k(
    const unsigned short* __restrict__ hQf, const unsigned short* __restrict__ hnV,
    const int* __restrict__ adj, const int* __restrict__ kptr,
    float* __restrict__ pl, unsigned short* __restrict__ pO, int T) {
  __shared__ __align__(16) unsigned short sK[2][8192];      // 16KB x2
  __shared__ __align__(16) unsigned short sV[2][8192];      // 16KB x2
  __shared__ __align__(16) unsigned short sP[4][2][16][40]; // per-wave/subtile P

  const int tid = threadIdx.x, w = tid >> 6, l = tid & 63, lr = l & 15, lg = l >> 4;
  const int c = blockIdx.x, ty = blockIdx.y;
  const int i0 = ty * 128;
  const int kid = *kptr;
  if (i0 + 128 <= kid) return;  // whole tile identity: comb_k handles it

  const int r0 = i0 + w * 32;  // this wave's 32 rows

  short8 qf[2][8];  // Q A-frags, 2 row-subtiles
#pragma unroll
  for (int rt = 0; rt < 2; ++rt)
#pragma unroll
    for (int kk = 0; kk < 8; ++kk)
      qf[rt][kk] =
          *(const short8*)(hQf + ((size_t)(((r0 >> 4) + rt) * 8 + kk) * 64 + l) * 8);

  f32x4 Oacc[2][16];
#pragma unroll
  for (int rt = 0; rt < 2; ++rt)
#pragma unroll
    for (int nt = 0; nt < 16; ++nt) Oacc[rt][nt] = (f32x4){0.f, 0.f, 0.f, 0.f};
  float lsum[2][4] = {{0.f, 0.f, 0.f, 0.f}, {0.f, 0.f, 0.f, 0.f}};
  const float c1 = 0.09016844005556021f;  // log2(e)/sqrt(256)

  const int jt0 = c * T;

  // ---- prologue: stage tile jt0 into buf 0 ----
  {
    const unsigned short* srcK = hQf + (size_t)jt0 * 8192;
    const unsigned short* srcV = hnV + (size_t)jt0 * 8192;
#pragma unroll
    for (int s = 0; s < 4; ++s) {
      const int so = (w * 4 + s) * 512;
      gld16(srcK + so + l * 8, &sK[0][so]);
      gld16(srcV + so + l * 8, &sV[0][so]);
    }
  }
  __syncthreads();

  for (int t = 0; t < T; ++t) {
    const int cur = t & 1;
    const int jt = jt0 + t;

    // adj loads for THIS iter (issued first; consumed after QK MFMAs)
    int av[2][2][4];
#pragma unroll
    for (int rt = 0; rt < 2; ++rt)
#pragma unroll
      for (int nt = 0; nt < 2; ++nt)
#pragma unroll
        for (int q = 0; q < 4; ++q)
          av[rt][nt][q] =
              adj[(size_t)(r0 + rt * 16 + lg * 4 + q) * NN + jt * 32 + nt * 16 + lr];

    if (t + 1 < T) {  // stage next tile into other buffer
      const int jn = jt + 1;
      const unsigned short* srcK = hQf + (size_t)jn * 8192;
      const unsigned short* srcV = hnV + (size_t)jn * 8192;
#pragma unroll
      for (int s = 0; s < 4; ++s) {
        const int so = (w * 4 + s) * 512;
        gld16(srcK + so + l * 8, &sK[cur ^ 1][so]);
        gld16(srcV + so + l * 8, &sV[cur ^ 1][so]);
      }
    }

    // ---- S = Q . K^T (K=256): 16 LDS frag reads -> 32 MFMAs (2x reuse) ----
    f32x4 S2[2][2];
#pragma unroll
    for (int rt = 0; rt < 2; ++rt)
#pragma unroll
      for (int nt = 0; nt < 2; ++nt) S2[rt][nt] = (f32x4){0.f, 0.f, 0.f, 0.f};
#pragma unroll
    for (int kk = 0; kk < 8; ++kk)
#pragma unroll
      for (int nt = 0; nt < 2; ++nt) {
        short8 bf = *(const short8*)(&sK[cur][(nt * 8 + kk) * 512 + l * 8]);
        S2[0][nt] = mfma16(qf[0][kk], bf, S2[0][nt]);
        S2[1][nt] = mfma16(qf[1][kk], bf, S2[1][nt]);
      }

    // ---- masked softmax numerators (pure sums, no max tracking) ----
#pragma unroll
    for (int rt = 0; rt < 2; ++rt) {
      float p0[4], p1[4];
#pragma unroll
      for (int q = 0; q < 4; ++q) {
        float sv0 = av[rt][0][q] ? fminf(S2[rt][0][q] * c1, 60.f) : NEGB;
        float sv1 = av[rt][1][q] ? fminf(S2[rt][1][q] * c1, 60.f) : NEGB;
        p0[q] = __builtin_amdgcn_exp2f(sv0);  // masked -> 0
        p1[q] = __builtin_amdgcn_exp2f(sv1);
        lsum[rt][q] += p0[q] + p1[q];
      }
#pragma unroll
      for (int q = 0; q < 4; ++q) {
        sP[w][rt][lg * 4 + q][lr] = f2bf(p0[q]);
        sP[w][rt][lg * 4 + q][16 + lr] = f2bf(p1[q]);
      }
    }

    // ---- PV: 16 LDS V-frag reads -> 32 MFMAs (2x reuse) ----
    short8 pa0 = *(const short8*)(&sP[w][0][lr][lg * 8]);
    short8 pa1 = *(const short8*)(&sP[w][1][lr][lg * 8]);
#pragma unroll
    for (int cnt = 0; cnt < 16; ++cnt) {
      short8 vf = *(const short8*)(&sV[cur][cnt * 512 + l * 8]);
      Oacc[0][cnt] = mfma16(pa0, vf, Oacc[0][cnt]);
      Oacc[1][cnt] = mfma16(pa1, vf, Oacc[1][cnt]);
    }
    __syncthreads();  // drains staging vmcnt; protects both buffers
  }

  // ---- reduce denominators over lr, write partials ----
#pragma unroll
  for (int rt = 0; rt < 2; ++rt)
#pragma unroll
    for (int q = 0; q < 4; ++q) {
      float s = lsum[rt][q];
#pragma unroll
      for (int off = 1; off < 16; off <<= 1) s += __shfl_xor(s, off);
      if (lr == 0) pl[(size_t)c * NN + r0 + rt * 16 + lg * 4 + q] = s;
    }
#pragma unroll
  for (int cnt = 0; cnt < 16; ++cnt)
#pragma unroll
    for (int rt = 0; rt < 2; ++rt)
#pragma unroll
      for (int q = 0; q < 4; ++q) {
        int row = r0 + rt * 16 + lg * 4 + q;
        pO[((size_t)c * NN + row) * DD + cnt * 16 + lr] = f2bf(Oacc[rt][cnt][q]);
      }
}

// ---- combine chunks + epilogue: 4 rows/block, ushort4 lanes ---------------
__global__ __launch_bounds__(256) void comb_k(const float* __restrict__ pl,
                                              const unsigned short* __restrict__ pO,
                                              const unsigned short* __restrict__ hnb,
                                              const int* __restrict__ kptr,
                                              float* __restrict__ out, int S) {
  const int row = blockIdx.x * 4 + (threadIdx.x >> 6);
  const int col = (threadIdx.x & 63) * 4;
  const int kid = *kptr;
  ushort4 hv = *(const ushort4*)(hnb + (size_t)row * DD + col);
  float v0 = bf2f(hv.x), v1 = bf2f(hv.y), v2 = bf2f(hv.z), v3 = bf2f(hv.w);
  float4 r;
  if (row < kid) {
    r.x = v0; r.y = v1; r.z = v2; r.w = v3;
  } else {
    float L = 0.f, a0 = 0.f, a1 = 0.f, a2 = 0.f, a3 = 0.f;
    for (int cc = 0; cc < S; ++cc) {
      L += pl[(size_t)cc * NN + row];
      ushort4 ov = *(const ushort4*)(pO + ((size_t)cc * NN + row) * DD + col);
      a0 += bf2f(ov.x); a1 += bf2f(ov.y); a2 += bf2f(ov.z); a3 += bf2f(ov.w);
    }
    float inv = 0.5f / L;
    r.x = a0 * inv + 0.5f * v0; r.y = a1 * inv + 0.5f * v1;
    r.z = a2 * inv + 0.5f * v2; r.w = a3 * inv + 0.5f * v3;
  }
  r.x = fmaxf(r.x, 0.f); r.y = fmaxf(r.y, 0.f);
  r.z = fmaxf(r.z, 0.f); r.w = fmaxf(r.w, 0.f);
  *(float4*)(out + (size_t)row * DD + col) = r;
}

extern "C" void kernel_launch(void* const* d_in, const int* in_sizes, int n_in,
                              void* d_out, int out_size, void* d_ws, size_t ws_size,
                              hipStream_t stream) {
  const float* h = (const float*)d_in[0];
  const int* adj = (const int*)d_in[1];
  const float* W = (const float*)d_in[2];
  const float* b = (const float*)d_in[3];
  float* out = (float*)d_out;

  char* ws = (char*)d_ws;
  const size_t MB4 = (size_t)NN * DD * 2;  // 4 MiB
  int* kbuf = (int*)ws;
  unsigned short* hQf = (unsigned short*)(ws + 256);
  unsigned short* hnb = (unsigned short*)(ws + 256 + MB4);
  unsigned short* hnV = (unsigned short*)(ws + 256 + 2 * MB4);
  unsigned short* Wf = (unsigned short*)(ws + 256 + 3 * MB4);  // 128 KiB
  char* dyn = ws + 256 + 3 * MB4 + (256 << 10);

  size_t fixed = 256 + 3 * MB4 + (256 << 10);
  int S = 16;
  while (S > 1 && fixed + (size_t)S * NN * (DD * 2 + 4) > ws_size) S >>= 1;
  const int T = 256 / S;

  float* pl = (float*)dyn;
  unsigned short* pO = (unsigned short*)(pl + (size_t)S * NN);

  hipMemsetAsync(kbuf, 0, 4, stream);
  hipLaunchKernelGGL(prep_k, dim3(2112), dim3(256), 0, stream, h, W, adj, hQf, Wf, kbuf);
  hipLaunchKernelGGL(hnew_k, dim3(NN / 64), dim3(256), 0, stream, hQf, Wf, b, hnb, hnV);
  hipLaunchKernelGGL(attn_k, dim3(S, NN / 128), dim3(256), 0, stream,
                     hQf, hnV, adj, kbuf, pl, pO, T);
  hipLaunchKernelGGL(comb_k, dim3(NN / 4), dim3(256), 0, stream, pl, pO, hnb, kbuf, out, S);
}

// Round 10
// 106.081 us; speedup vs baseline: 1.4214x; 1.4214x over previous
//
#include <hip/hip_runtime.h>

// GAT layer fused, MI355X gfx950 — v10: v8's proven attn (16 rows/wave,
// dbuf, 2x unroll, XCD-pinned chunks) + setprio around MFMA clusters;
// fused prep (conv|count|packW); hnew split by col halves (2x grid).
// Pipeline: memset -> prep_k -> hnew_k -> attn_k -> comb_k.

typedef __attribute__((ext_vector_type(8))) short short8;   // 8 x bf16 (4 VGPR)
typedef __attribute__((ext_vector_type(4))) float f32x4;    // MFMA C/D frag

#define NN 8192
#define DD 256
#define NEGB -1.2983e16f  // -9e15 * log2(e): NEG_BIG in base-2 softmax domain

__device__ __forceinline__ unsigned short f2bf(float f) {
  unsigned u = __builtin_bit_cast(unsigned, f);
  u += 0x7FFFu + ((u >> 16) & 1u);  // RNE
  return (unsigned short)(u >> 16);
}
__device__ __forceinline__ float bf2f(unsigned short s) {
  unsigned u = ((unsigned)s) << 16;
  return __builtin_bit_cast(float, u);
}
__device__ __forceinline__ f32x4 mfma16(short8 a, short8 b, f32x4 c) {
  return __builtin_amdgcn_mfma_f32_16x16x32_bf16(a, b, c, 0, 0, 0);
}
// async global->LDS, 16B per lane; lds ptr wave-uniform base
__device__ __forceinline__ void gld16(const unsigned short* g, unsigned short* l) {
  __builtin_amdgcn_global_load_lds(
      (const __attribute__((address_space(1))) void*)g,
      (__attribute__((address_space(3))) void*)l, 16, 0, 0);
}

// ---- fused prep: conv_h (blocks 0..2047) | count_k (2048..2079) | pack_wf --
__global__ __launch_bounds__(256) void prep_k(const float* __restrict__ h,
                                              const float* __restrict__ W,
                                              const int* __restrict__ adj,
                                              unsigned short* __restrict__ hQf,
                                              unsigned short* __restrict__ Wf,
                                              int* __restrict__ kout) {
  const int bx = blockIdx.x, tid = threadIdx.x;
  if (bx < 2048) {  // h (f32) -> hQf bf16 MFMA frags
    int gid = bx * 256 + tid;
    int i = gid >> 6, k4 = (gid & 63) * 4;
    float4 v = *(const float4*)(h + (size_t)i * DD + k4);
    size_t off = ((size_t)((i >> 4) * 8 + (k4 >> 5)) * 64 +
                  (((k4 >> 3) & 3) * 16 + (i & 15))) * 8 + (k4 & 7);
    ushort4 o;
    o.x = f2bf(v.x); o.y = f2bf(v.y); o.z = f2bf(v.z); o.w = f2bf(v.w);
    *(ushort4*)(hQf + off) = o;
  } else if (bx < 2080) {  // k = sum(adj[:,0] != 0)
    __shared__ int red[256];
    int gid = (bx - 2048) * 256 + tid;
    red[tid] = (adj[(size_t)gid * NN] != 0);
    __syncthreads();
    for (int off = 128; off; off >>= 1) {
      if (tid < off) red[tid] += red[tid + off];
      __syncthreads();
    }
    if (tid == 0) atomicAdd(kout, red[0]);
  } else {  // W -> bf16 B-frags
    int gid = (bx - 2080) * 256 + tid;
    int l = gid & 63, f = gid >> 6, n16 = f >> 3, kk = f & 7;
    int lr = l & 15, lg = l >> 4;
    const float* src = W + (size_t)(n16 * 16 + lr) * DD + kk * 32 + lg * 8;
    float4 w0 = *(const float4*)src, w1 = *(const float4*)(src + 4);
    short8 o;
    o[0] = (short)f2bf(w0.x); o[1] = (short)f2bf(w0.y);
    o[2] = (short)f2bf(w0.z); o[3] = (short)f2bf(w0.w);
    o[4] = (short)f2bf(w1.x); o[5] = (short)f2bf(w1.y);
    o[6] = (short)f2bf(w1.z); o[7] = (short)f2bf(w1.w);
    *(short8*)(Wf + (size_t)gid * 8) = o;
  }
}

// ---- h_new = h @ W^T + b -> hnb + hnV frags; 256 blocks (row x col-half) --
__global__ __launch_bounds__(256) void hnew_k(const unsigned short* __restrict__ hQf,
                                              const unsigned short* __restrict__ Wf,
                                              const float* __restrict__ bias,
                                              unsigned short* __restrict__ hnb,
                                              unsigned short* __restrict__ hnV) {
  const int tid = threadIdx.x, w = tid >> 6, l = tid & 63, lr = l & 15, lg = l >> 4;
  const int row0 = (blockIdx.x >> 1) * 64 + w * 16;
  const int nt0 = (blockIdx.x & 1) * 8;

  short8 a[8];
#pragma unroll
  for (int kk = 0; kk < 8; ++kk)
    a[kk] = *(const short8*)(hQf + ((size_t)((row0 >> 4) * 8 + kk) * 64 + l) * 8);

  f32x4 acc[8];
#pragma unroll
  for (int nt = 0; nt < 8; ++nt) acc[nt] = (f32x4){0.f, 0.f, 0.f, 0.f};

#pragma unroll
  for (int kk = 0; kk < 8; ++kk)
#pragma unroll
    for (int nt = 0; nt < 8; ++nt) {
      short8 bf = *(const short8*)(Wf + ((size_t)((nt0 + nt) * 8 + kk) * 64 + l) * 8);
      acc[nt] = mfma16(a[kk], bf, acc[nt]);
    }
  const int rowbase = row0 + lg * 4;  // q = 0..3 contiguous within 8-run
#pragma unroll
  for (int nt = 0; nt < 8; ++nt) {
    const int col = (nt0 + nt) * 16 + lr;
    const float bv = bias[col];
    unsigned short r16[4];
#pragma unroll
    for (int q = 0; q < 4; ++q) r16[q] = f2bf(acc[nt][q] + bv);
#pragma unroll
    for (int q = 0; q < 4; ++q) hnb[(size_t)(rowbase + q) * DD + col] = r16[q];
    ushort4 o4 = {r16[0], r16[1], r16[2], r16[3]};
    *(ushort4*)(hnV + ((size_t)((rowbase >> 5) * 16 + nt0 + nt) * 64 +
                       ((rowbase >> 3) & 3) * 16 + lr) * 8 + (rowbase & 7)) = o4;
  }
}

// ---- flash attention partials (v8 structure + setprio) --------------------
// Grid (S=16 chunks, 128 tiles): chunk = blockIdx.x so chunk%8 = XCD -> each
// XCD L2 caches its 2 chunks' K/V frags. 4 waves x 16 rows; dbuf LDS;
// manual 2x unroll (fixed buffers, alternating mask regs); 1 barrier/iter.
__global__ __launch_bounds__(256, 2) void attn_k(
    const unsigned short* __restrict__ hQf, const unsigned short* __restrict__ hnV,
    const int* __restrict__ adj, const int* __restrict__ kptr,
    float* __restrict__ pl, unsigned short* __restrict__ pO, int T) {
  __shared__ __align__(16) unsigned short sK[2][8192];   // 16KB x2
  __shared__ __align__(16) unsigned short sV[2][8192];   // 16KB x2
  __shared__ __align__(16) unsigned short sP[4][16][40]; // per-wave P transpose

  const int tid = threadIdx.x, w = tid >> 6, l = tid & 63, lr = l & 15, lg = l >> 4;
  const int c = blockIdx.x, ty = blockIdx.y;
  const int i0 = ty * 64;
  const int kid = *kptr;
  if (i0 + 64 <= kid) return;  // whole tile identity: comb_k handles it

  const int r0 = i0 + w * 16;  // this wave's 16 rows

  short8 qf[8];  // Q A-frags
#pragma unroll
  for (int kk = 0; kk < 8; ++kk)
    qf[kk] = *(const short8*)(hQf + ((size_t)((r0 >> 4) * 8 + kk) * 64 + l) * 8);

  f32x4 Oacc[16];
#pragma unroll
  for (int nt = 0; nt < 16; ++nt) Oacc[nt] = (f32x4){0.f, 0.f, 0.f, 0.f};
  float lsum[4] = {0.f, 0.f, 0.f, 0.f};   // per-lane partial denominators
  const float c1 = 0.09016844005556021f;  // log2(e)/sqrt(256)

  int arow[4];
#pragma unroll
  for (int q = 0; q < 4; ++q) arow[q] = (r0 + lg * 4 + q) * NN;

  const int jt0 = c * T;

  // ---- prologue: stage tile jt0 into buf 0, load its adj into avA ----
  {
    const unsigned short* srcK = hQf + (size_t)jt0 * 8192;
    const unsigned short* srcV = hnV + (size_t)jt0 * 8192;
#pragma unroll
    for (int s = 0; s < 4; ++s) {
      const int so = (w * 4 + s) * 512;
      gld16(srcK + so + l * 8, &sK[0][so]);
      gld16(srcV + so + l * 8, &sV[0][so]);
    }
  }
  int avA[8], avB[8];
#pragma unroll
  for (int nt = 0; nt < 2; ++nt)
#pragma unroll
    for (int q = 0; q < 4; ++q)
      avA[nt * 4 + q] = adj[(size_t)arow[q] + jt0 * 32 + nt * 16 + lr];
  __syncthreads();

#define ATTN_ITER(T_IDX, CUR, MC, MN)                                          \
  {                                                                            \
    const int t_ = (T_IDX);                                                    \
    if (t_ + 1 < T) { /* stage next tile into other buffer, masks into MN */   \
      const int jn = jt0 + t_ + 1;                                             \
      const unsigned short* srcK = hQf + (size_t)jn * 8192;                    \
      const unsigned short* srcV = hnV + (size_t)jn * 8192;                    \
      _Pragma("unroll") for (int s = 0; s < 4; ++s) {                          \
        const int so = (w * 4 + s) * 512;                                      \
        gld16(srcK + so + l * 8, &sK[(CUR) ^ 1][so]);                          \
        gld16(srcV + so + l * 8, &sV[(CUR) ^ 1][so]);                          \
      }                                                                        \
      _Pragma("unroll") for (int nt = 0; nt < 2; ++nt)                         \
        _Pragma("unroll") for (int q = 0; q < 4; ++q)                          \
          MN[nt * 4 + q] = adj[(size_t)arow[q] + jn * 32 + nt * 16 + lr];      \
    }                                                                          \
    f32x4 S2[2];                                                               \
    S2[0] = (f32x4){0.f, 0.f, 0.f, 0.f};                                       \
    S2[1] = (f32x4){0.f, 0.f, 0.f, 0.f};                                       \
    __builtin_amdgcn_s_setprio(1);                                             \
    _Pragma("unroll") for (int kk = 0; kk < 8; ++kk)                           \
      _Pragma("unroll") for (int nt = 0; nt < 2; ++nt) {                       \
        short8 bf = *(const short8*)(&sK[(CUR)][(nt * 8 + kk) * 512 + l * 8]); \
        S2[nt] = mfma16(qf[kk], bf, S2[nt]);                                   \
      }                                                                        \
    __builtin_amdgcn_s_setprio(0);                                             \
    float p0[4], p1[4];                                                        \
    _Pragma("unroll") for (int q = 0; q < 4; ++q) {                            \
      float sv0 = MC[q] ? fminf(S2[0][q] * c1, 60.f) : NEGB;                   \
      float sv1 = MC[4 + q] ? fminf(S2[1][q] * c1, 60.f) : NEGB;               \
      p0[q] = __builtin_amdgcn_exp2f(sv0);                                     \
      p1[q] = __builtin_amdgcn_exp2f(sv1);                                     \
      lsum[q] += p0[q] + p1[q];                                                \
    }                                                                          \
    _Pragma("unroll") for (int q = 0; q < 4; ++q) {                            \
      sP[w][lg * 4 + q][lr] = f2bf(p0[q]);                                     \
      sP[w][lg * 4 + q][16 + lr] = f2bf(p1[q]);                                \
    }                                                                          \
    short8 pa = *(const short8*)(&sP[w][lr][lg * 8]);                          \
    __builtin_amdgcn_s_setprio(1);                                             \
    _Pragma("unroll") for (int cnt = 0; cnt < 16; ++cnt) {                     \
      short8 vf = *(const short8*)(&sV[(CUR)][cnt * 512 + l * 8]);             \
      Oacc[cnt] = mfma16(pa, vf, Oacc[cnt]);                                   \
    }                                                                          \
    __builtin_amdgcn_s_setprio(0);                                             \
    __syncthreads();                                                           \
  }

  for (int tt = 0; tt < T; tt += 2) {
    ATTN_ITER(tt, 0, avA, avB);      // compute buf0/avA, stage buf1/avB
    ATTN_ITER(tt + 1, 1, avB, avA);  // compute buf1/avB, stage buf0/avA
  }
#undef ATTN_ITER

  // ---- reduce denominators over lr (within 16-lane group), write partials --
#pragma unroll
  for (int q = 0; q < 4; ++q) {
#pragma unroll
    for (int off = 1; off < 16; off <<= 1) lsum[q] += __shfl_xor(lsum[q], off);
    if (lr == 0) pl[(size_t)c * NN + r0 + lg * 4 + q] = lsum[q];
  }
#pragma unroll
  for (int cnt = 0; cnt < 16; ++cnt)
#pragma unroll
    for (int q = 0; q < 4; ++q) {
      int row = r0 + lg * 4 + q;
      pO[((size_t)c * NN + row) * DD + cnt * 16 + lr] = f2bf(Oacc[cnt][q]);
    }
}

// ---- combine chunks + epilogue: 4 rows/block, ushort4 lanes ---------------
__global__ __launch_bounds__(256) void comb_k(const float* __restrict__ pl,
                                              const unsigned short* __restrict__ pO,
                                              const unsigned short* __restrict__ hnb,
                                              const int* __restrict__ kptr,
                                              float* __restrict__ out, int S) {
  const int row = blockIdx.x * 4 + (threadIdx.x >> 6);
  const int col = (threadIdx.x & 63) * 4;
  const int kid = *kptr;
  ushort4 hv = *(const ushort4*)(hnb + (size_t)row * DD + col);
  float v0 = bf2f(hv.x), v1 = bf2f(hv.y), v2 = bf2f(hv.z), v3 = bf2f(hv.w);
  float4 r;
  if (row < kid) {
    r.x = v0; r.y = v1; r.z = v2; r.w = v3;
  } else {
    float L = 0.f, a0 = 0.f, a1 = 0.f, a2 = 0.f, a3 = 0.f;
    for (int cc = 0; cc < S; ++cc) {
      L += pl[(size_t)cc * NN + row];
      ushort4 ov = *(const ushort4*)(pO + ((size_t)cc * NN + row) * DD + col);
      a0 += bf2f(ov.x); a1 += bf2f(ov.y); a2 += bf2f(ov.z); a3 += bf2f(ov.w);
    }
    float inv = 0.5f / L;
    r.x = a0 * inv + 0.5f * v0; r.y = a1 * inv + 0.5f * v1;
    r.z = a2 * inv + 0.5f * v2; r.w = a3 * inv + 0.5f * v3;
  }
  r.x = fmaxf(r.x, 0.f); r.y = fmaxf(r.y, 0.f);
  r.z = fmaxf(r.z, 0.f); r.w = fmaxf(r.w, 0.f);
  *(float4*)(out + (size_t)row * DD + col) = r;
}

extern "C" void kernel_launch(void* const* d_in, const int* in_sizes, int n_in,
                              void* d_out, int out_size, void* d_ws, size_t ws_size,
                              hipStream_t stream) {
  const float* h = (const float*)d_in[0];
  const int* adj = (const int*)d_in[1];
  const float* W = (const float*)d_in[2];
  const float* b = (const float*)d_in[3];
  float* out = (float*)d_out;

  char* ws = (char*)d_ws;
  const size_t MB4 = (size_t)NN * DD * 2;  // 4 MiB
  int* kbuf = (int*)ws;
  unsigned short* hQf = (unsigned short*)(ws + 256);
  unsigned short* hnb = (unsigned short*)(ws + 256 + MB4);
  unsigned short* hnV = (unsigned short*)(ws + 256 + 2 * MB4);
  unsigned short* Wf = (unsigned short*)(ws + 256 + 3 * MB4);  // 128 KiB
  char* dyn = ws + 256 + 3 * MB4 + (256 << 10);

  size_t fixed = 256 + 3 * MB4 + (256 << 10);
  int S = 16;
  while (S > 1 && fixed + (size_t)S * NN * (DD * 2 + 4) > ws_size) S >>= 1;
  const int T = 256 / S;

  float* pl = (float*)dyn;
  unsigned short* pO = (unsigned short*)(pl + (size_t)S * NN);

  hipMemsetAsync(kbuf, 0, 4, stream);
  hipLaunchKernelGGL(prep_k, dim3(2112), dim3(256), 0, stream, h, W, adj, hQf, Wf, kbuf);
  hipLaunchKernelGGL(hnew_k, dim3(256), dim3(256), 0, stream, hQf, Wf, b, hnb, hnV);
  hipLaunchKernelGGL(attn_k, dim3(S, NN / 64), dim3(256), 0, stream,
                     hQf, hnV, adj, kbuf, pl, pO, T);
  hipLaunchKernelGGL(comb_k, dim3(NN / 4), dim3(256), 0, stream, pl, pO, hnb, kbuf, out, S);
}